// Round 6
// baseline (167.710 us; speedup 1.0000x reference)
//
#include <hip/hip_runtime.h>
#include <math.h>

// Problem constants (match reference)
constexpr int kVerts = 5000;
constexpr int kFaces = 10000;
constexpr int kHalf  = kFaces / 2;
constexpr int kPts   = 16384;   // BATCH * N_PTS = 2 * 8192
constexpr int kOuter = 4;
constexpr int kInner = 50;
constexpr int kILP   = 2;       // points per solve thread
constexpr int kSolveThreads = kPts / kILP;   // 8192

#define SCALE 10.0f

// ---------------------------------------------------------------------------
// Compile-time Adam bias-correction table, rb[2t]=1/(1-0.9^(t+1)),
// rb[2t+1]=1/(1-0.999^(t+1)) (paired for a single s_load_dwordx2).
// ---------------------------------------------------------------------------
struct BiasTab { float rb[2 * kInner]; };
constexpr BiasTab make_tab() {
    BiasTab t{};
    float b1 = 1.0f, b2 = 1.0f;
    for (int i = 0; i < kInner; ++i) {
        b1 *= 0.9f; b2 *= 0.999f;
        t.rb[2 * i + 0] = 1.0f / (1.0f - b1);
        t.rb[2 * i + 1] = 1.0f / (1.0f - b2);
    }
    return t;
}
__device__ constexpr BiasTab kTab = make_tab();

// ---------------------------------------------------------------------------
// Kernel 0: precompute triangle centers once (bit-identical *_rn formula).
// cent[f] = (cx, cy, cz, cc = |c|^2)
// ---------------------------------------------------------------------------
__global__ __launch_bounds__(256)
void centers_kernel(const float* __restrict__ mesh_V,
                    const int*   __restrict__ mesh_F,
                    float4*      __restrict__ cent)
{
    const int f = blockIdx.x * 256 + threadIdx.x;
    if (f >= kFaces) return;
    const int i0 = mesh_F[f * 3 + 0];
    const int i1 = mesh_F[f * 3 + 1];
    const int i2 = mesh_F[f * 3 + 2];
    const float cx = __fdiv_rn(__fadd_rn(__fadd_rn(mesh_V[i0*3+0], mesh_V[i1*3+0]), mesh_V[i2*3+0]), 3.0f);
    const float cy = __fdiv_rn(__fadd_rn(__fadd_rn(mesh_V[i0*3+1], mesh_V[i1*3+1]), mesh_V[i2*3+1]), 3.0f);
    const float cz = __fdiv_rn(__fadd_rn(__fadd_rn(mesh_V[i0*3+2], mesh_V[i1*3+2]), mesh_V[i2*3+2]), 3.0f);
    const float cc = __fadd_rn(__fadd_rn(__fmul_rn(cx, cx), __fmul_rn(cy, cy)),
                               __fmul_rn(cz, cz));
    cent[f] = make_float4(cx, cy, cz, cc);
}

// ---------------------------------------------------------------------------
// Kernel 1: KNN (K=1) — BYTE-IDENTICAL to round 5 (frozen; ~48 us).
// ---------------------------------------------------------------------------
#define KNN_PARTS 16

__global__ __launch_bounds__(1024)
void knn_kernel(const float* __restrict__ verts,
                const float4* __restrict__ cent,
                float*        __restrict__ ws_d2,   // [2][kPts]
                int*          __restrict__ ws_f)    // [2][kPts]
{
    __shared__ float s_best[1024];
    __shared__ int   s_bestf[1024];

    const int tid  = threadIdx.x;
    const int lane = tid & 63;
    const int part = __builtin_amdgcn_readfirstlane(tid >> 6);   // 0..15
    const int pg   = blockIdx.x >> 1;
    const int half = blockIdx.x & 1;
    const int p    = pg * 64 + lane;

    const float qx = verts[p * 3 + 0];
    const float qy = verts[p * 3 + 1];
    const float qz = verts[p * 3 + 2];
    const float q2 = __fadd_rn(__fadd_rn(__fmul_rn(qx, qx), __fmul_rn(qy, qy)),
                               __fmul_rn(qz, qz));

    const int fbeg = half * kHalf + (part * kHalf) / KNN_PARTS;
    const int fend = half * kHalf + ((part + 1) * kHalf) / KNN_PARTS;

    float bd0 = INFINITY, bd1 = INFINITY, bd2 = INFINITY, bd3 = INFINITY;
    int   bf0 = 0x7fffffff, bf1 = 0x7fffffff, bf2 = 0x7fffffff, bf3 = 0x7fffffff;

#define KNN_EVAL(FF, C, BD, BF)                                                       \
    {                                                                                 \
        const float dot = __fadd_rn(__fadd_rn(__fmul_rn(qx, (C).x),                   \
                                              __fmul_rn(qy, (C).y)),                  \
                                    __fmul_rn(qz, (C).z));                            \
        const float d2 = __fsub_rn(__fadd_rn(q2, (C).w), __fmul_rn(2.0f, dot));       \
        if (d2 < (BD)) { (BD) = d2; (BF) = (FF); }                                    \
    }

    int f = fbeg;
#pragma unroll 4
    for (; f + 4 <= fend; f += 4) {
        const float4 c0 = cent[f + 0];   // uniform address -> scalar load
        const float4 c1 = cent[f + 1];
        const float4 c2 = cent[f + 2];
        const float4 c3 = cent[f + 3];
        KNN_EVAL(f + 0, c0, bd0, bf0);
        KNN_EVAL(f + 1, c1, bd1, bf1);
        KNN_EVAL(f + 2, c2, bd2, bf2);
        KNN_EVAL(f + 3, c3, bd3, bf3);
    }
    for (; f < fend; ++f) {
        const float4 c0 = cent[f];
        KNN_EVAL(f, c0, bd0, bf0);
    }
#undef KNN_EVAL

    if (bd1 < bd0 || (bd1 == bd0 && bf1 < bf0)) { bd0 = bd1; bf0 = bf1; }
    if (bd3 < bd2 || (bd3 == bd2 && bf3 < bf2)) { bd2 = bd3; bf2 = bf3; }
    if (bd2 < bd0 || (bd2 == bd0 && bf2 < bf0)) { bd0 = bd2; bf0 = bf2; }

    s_best[tid]  = bd0;
    s_bestf[tid] = bf0;
    __syncthreads();
    if (part == 0) {
        float best  = bd0;
        int   bestf = bf0;
        for (int k = 1; k < KNN_PARTS; ++k) {
            const float ob = s_best[tid + 64 * k];
            const int   of = s_bestf[tid + 64 * k];
            if (ob < best || (ob == best && of < bestf)) { best = ob; bestf = of; }
        }
        ws_d2[half * kPts + p] = best;
        ws_f [half * kPts + p] = bestf;
    }
}

// ---------------------------------------------------------------------------
// Kernel 2: per-point solve with 2 INDEPENDENT POINTS PER THREAD.
// Round-5 counters: 1 wave/SIMD, 33% issue on the busy SIMD, ~700 of
// ~1050 cyc/iter are chain-latency stalls. Interleaving two independent
// Adam chains per thread fills those stalls with the other chain's issue:
// wall/iter = max(chain ~1050, 2 x issue ~700) -> ~2x per point.
// Per-point math identical to round 5 (same expression trees).
// 128 blocks x 64 threads; thread t handles p = t and p = t + 8192.
// ---------------------------------------------------------------------------
struct PS {
    float V0x,V0y,V0z, V1x,V1y,V1z, V2x,V2y,V2z;
    float N0x,N0y,N0z, N1x,N1y,N1z, N2x,N2y,N2z;
    float E0x,E0y,E0z, E1x,E1y,E1z;
    float F0x,F0y,F0z, F1x,F1y,F1z;
    float qx,qy,qz, tx,ty,tz;
    float vwu, vwv;
    float du, dv, dd;
    float mAu, mAv, mAd, vAu, vAv, vAd;
};

__device__ __forceinline__ void adam_iter(PS& s, float rb1, float rb2)
{
    const float GS = 2.0f / (3.0f * 16384.0f);
    const float B1 = 0.9f,  ONE_M_B1 = 1.0f - 0.9f;
    const float B2 = 0.999f, ONE_M_B2 = 1.0f - 0.999f;

    const float bu = s.vwu + s.du;
    const float bv = s.vwv + s.dv;
    const float bw = (1.0f - bu) - bv;

    const float cVx = ((bu * s.V0x + bv * s.V1x) + bw * s.V2x) * SCALE;
    const float cVy = ((bu * s.V0y + bv * s.V1y) + bw * s.V2y) * SCALE;
    const float cVz = ((bu * s.V0z + bv * s.V1z) + bw * s.V2z) * SCALE;

    const float nrx = (bu * s.N0x + bv * s.N1x) + bw * s.N2x;
    const float nry = (bu * s.N0y + bv * s.N1y) + bw * s.N2y;
    const float nrz = (bu * s.N0z + bv * s.N1z) + bw * s.N2z;
    const float nn  = (nrx * nrx + nry * nry) + nrz * nrz;
    const float inv = __builtin_amdgcn_rsqf(nn);
    const float nhx = nrx * inv, nhy = nry * inv, nhz = nrz * inv;
    const float cNx = nhx * SCALE, cNy = nhy * SCALE, cNz = nhz * SCALE;

    const float rx = (cVx + cNx * s.dd) - s.tx;
    const float ry = (cVy + cNy * s.dd) - s.ty;
    const float rz = (cVz + cNz * s.dd) - s.tz;

    const float rv0  = (rx * s.E0x + ry * s.E0y) + rz * s.E0z;
    const float rv1  = (rx * s.E1x + ry * s.E1y) + rz * s.E1z;
    const float rn0  = (rx * s.F0x + ry * s.F0y) + rz * s.F0z;
    const float rn1  = (rx * s.F1x + ry * s.F1y) + rz * s.F1z;
    const float nf0  = (nhx * s.F0x + nhy * s.F0y) + nhz * s.F0z;
    const float nf1  = (nhx * s.F1x + nhy * s.F1y) + nhz * s.F1z;
    const float nr_r = (nhx * rx + nhy * ry) + nhz * rz;

    const float gu = GS * (SCALE * rv0 + (s.dd * SCALE) * ((rn0 - nr_r * nf0) * inv));
    const float gv = GS * (SCALE * rv1 + (s.dd * SCALE) * ((rn1 - nr_r * nf1) * inv));
    const float gd = GS * (SCALE * nr_r);

    s.mAu = B1 * s.mAu + ONE_M_B1 * gu;
    s.mAv = B1 * s.mAv + ONE_M_B1 * gv;
    s.mAd = B1 * s.mAd + ONE_M_B1 * gd;
    s.vAu = B2 * s.vAu + ONE_M_B2 * (gu * gu);
    s.vAv = B2 * s.vAv + ONE_M_B2 * (gv * gv);
    s.vAd = B2 * s.vAd + ONE_M_B2 * (gd * gd);

    const float su = __builtin_amdgcn_rsqf(s.vAu * rb2 + 1e-16f);
    const float sv = __builtin_amdgcn_rsqf(s.vAv * rb2 + 1e-16f);
    const float sd = __builtin_amdgcn_rsqf(s.vAd * rb2 + 1e-16f);
    s.du -= 0.01f * (s.mAu * rb1) * su;
    s.dv -= 0.01f * (s.mAv * rb1) * sv;
    s.dd -= 0.01f * (s.mAd * rb1) * sd;
}

__global__ __launch_bounds__(64, 1)
void solve_kernel(const float* __restrict__ verts,
                  const float* __restrict__ mesh_V,
                  const float* __restrict__ mesh_N,
                  const int*   __restrict__ mesh_F,
                  const float* __restrict__ ws_d2,
                  const int*   __restrict__ ws_f,
                  float*       __restrict__ out)
{
    const int t = blockIdx.x * 64 + threadIdx.x;   // 0..8191
    PS s[kILP];

#pragma unroll
    for (int k = 0; k < kILP; ++k) {
        const int p = t + k * kSolveThreads;

        // merge halves: half 0 wins ties (lower indices) == first occurrence
        const float da = ws_d2[p];
        const float db = ws_d2[kPts + p];
        const int   fa = ws_f[p];
        const int   fb = ws_f[kPts + p];
        const int   f  = (db < da) ? fb : fa;
        out[p] = (float)f;

        s[k].qx = verts[p * 3 + 0];
        s[k].qy = verts[p * 3 + 1];
        s[k].qz = verts[p * 3 + 2];
        s[k].tx = s[k].qx * SCALE; s[k].ty = s[k].qy * SCALE; s[k].tz = s[k].qz * SCALE;

        const int i0 = mesh_F[f * 3 + 0];
        const int i1 = mesh_F[f * 3 + 1];
        const int i2 = mesh_F[f * 3 + 2];

        s[k].V0x = mesh_V[i0*3+0]; s[k].V0y = mesh_V[i0*3+1]; s[k].V0z = mesh_V[i0*3+2];
        s[k].V1x = mesh_V[i1*3+0]; s[k].V1y = mesh_V[i1*3+1]; s[k].V1z = mesh_V[i1*3+2];
        s[k].V2x = mesh_V[i2*3+0]; s[k].V2y = mesh_V[i2*3+1]; s[k].V2z = mesh_V[i2*3+2];
        s[k].N0x = mesh_N[i0*3+0]; s[k].N0y = mesh_N[i0*3+1]; s[k].N0z = mesh_N[i0*3+2];
        s[k].N1x = mesh_N[i1*3+0]; s[k].N1y = mesh_N[i1*3+1]; s[k].N1z = mesh_N[i1*3+2];
        s[k].N2x = mesh_N[i2*3+0]; s[k].N2y = mesh_N[i2*3+1]; s[k].N2z = mesh_N[i2*3+2];

        s[k].E0x = s[k].V0x - s[k].V2x; s[k].E0y = s[k].V0y - s[k].V2y; s[k].E0z = s[k].V0z - s[k].V2z;
        s[k].E1x = s[k].V1x - s[k].V2x; s[k].E1y = s[k].V1y - s[k].V2y; s[k].E1z = s[k].V1z - s[k].V2z;
        s[k].F0x = s[k].N0x - s[k].N2x; s[k].F0y = s[k].N0y - s[k].N2y; s[k].F0z = s[k].N0z - s[k].N2z;
        s[k].F1x = s[k].N1x - s[k].N2x; s[k].F1y = s[k].N1y - s[k].N2y; s[k].F1z = s[k].N1z - s[k].N2z;

        s[k].vwu = 1.0f / 3.0f; s[k].vwv = 1.0f / 3.0f;
    }

    for (int outer = 0; outer < kOuter; ++outer) {
#pragma unroll
        for (int k = 0; k < kILP; ++k) {
            const float bw0 = (1.0f - s[k].vwu) - s[k].vwv;
            const float px = ((s[k].vwu * s[k].V0x + s[k].vwv * s[k].V1x) + bw0 * s[k].V2x);
            const float py = ((s[k].vwu * s[k].V0y + s[k].vwv * s[k].V1y) + bw0 * s[k].V2y);
            const float pz = ((s[k].vwu * s[k].V0z + s[k].vwv * s[k].V1z) + bw0 * s[k].V2z);
            const float dx = px - s[k].qx, dy = py - s[k].qy, dz = pz - s[k].qz;
            s[k].dd = __builtin_amdgcn_sqrtf((dx * dx + dy * dy) + dz * dz);
            s[k].du = 0.0f; s[k].dv = 0.0f;
            s[k].mAu = 0.0f; s[k].mAv = 0.0f; s[k].mAd = 0.0f;
            s[k].vAu = 0.0f; s[k].vAv = 0.0f; s[k].vAd = 0.0f;
        }

#pragma unroll 2
        for (int it = 0; it < kInner; ++it) {
            const float rb1 = kTab.rb[2 * it + 0];   // uniform s_load_dwordx2
            const float rb2 = kTab.rb[2 * it + 1];
#pragma unroll
            for (int k = 0; k < kILP; ++k) {
                adam_iter(s[k], rb1, rb2);           // 2 independent chains interleave
            }
        }

#pragma unroll
        for (int k = 0; k < kILP; ++k) {
            s[k].vwu += s[k].du;
            s[k].vwv += s[k].dv;
        }
    }

#pragma unroll
    for (int k = 0; k < kILP; ++k) {
        const int p = t + k * kSolveThreads;
        out[kPts + 2 * p + 0] = s[k].vwu;
        out[kPts + 2 * p + 1] = s[k].vwv;
        out[3 * kPts + p]     = 0.0f;   // outlier_mask = False
    }
}

extern "C" void kernel_launch(void* const* d_in, const int* in_sizes, int n_in,
                              void* d_out, int out_size, void* d_ws, size_t ws_size,
                              hipStream_t stream) {
    const float* verts  = (const float*)d_in[0];
    const float* mesh_V = (const float*)d_in[1];
    const float* mesh_N = (const float*)d_in[2];
    const int*   mesh_F = (const int*)d_in[3];
    float* out = (float*)d_out;

    // workspace layout: centers | d2 candidates | face candidates
    float4* ws_cent = (float4*)d_ws;                                   // kFaces float4
    float*  ws_d2   = (float*)((char*)d_ws + kFaces * sizeof(float4)); // [2][kPts]
    int*    ws_f    = (int*)((char*)ws_d2 + 2 * kPts * sizeof(float)); // [2][kPts]

    hipLaunchKernelGGL(centers_kernel, dim3((kFaces + 255) / 256), dim3(256), 0, stream,
                       mesh_V, mesh_F, ws_cent);
    hipLaunchKernelGGL(knn_kernel,     dim3(2 * kPts / 64), dim3(1024), 0, stream,
                       verts, ws_cent, ws_d2, ws_f);
    hipLaunchKernelGGL(solve_kernel,   dim3(kSolveThreads / 64), dim3(64), 0, stream,
                       verts, mesh_V, mesh_N, mesh_F, ws_d2, ws_f, out);
}

// Round 7
// 148.868 us; speedup vs baseline: 1.1266x; 1.1266x over previous
//
#include <hip/hip_runtime.h>
#include <math.h>

// Problem constants (match reference)
constexpr int kVerts = 5000;
constexpr int kFaces = 10000;
constexpr int kPts   = 16384;   // BATCH * N_PTS = 2 * 8192
constexpr int kOuter = 4;
constexpr int kInner = 50;

#define SCALE 10.0f

// 2-wide fp32 vector: backend lowers <2 x float> arithmetic to v_pk_*_f32
// (one instruction driving BOTH solve chains -> half the issue slots/point).
typedef float v2 __attribute__((ext_vector_type(2)));

// ---------------------------------------------------------------------------
// Compile-time Adam bias-correction table (paired rb1/rb2 per step).
// ---------------------------------------------------------------------------
struct BiasTab { float rb[2 * kInner]; };
constexpr BiasTab make_tab() {
    BiasTab t{};
    float b1 = 1.0f, b2 = 1.0f;
    for (int i = 0; i < kInner; ++i) {
        b1 *= 0.9f; b2 *= 0.999f;
        t.rb[2 * i + 0] = 1.0f / (1.0f - b1);
        t.rb[2 * i + 1] = 1.0f / (1.0f - b2);
    }
    return t;
}
__device__ constexpr BiasTab kTab = make_tab();

// ---------------------------------------------------------------------------
// Kernel 0: precompute triangle centers once (bit-identical *_rn formula).
// ---------------------------------------------------------------------------
__global__ __launch_bounds__(256)
void centers_kernel(const float* __restrict__ mesh_V,
                    const int*   __restrict__ mesh_F,
                    float4*      __restrict__ cent)
{
    const int f = blockIdx.x * 256 + threadIdx.x;
    if (f >= kFaces) return;
    const int i0 = mesh_F[f * 3 + 0];
    const int i1 = mesh_F[f * 3 + 1];
    const int i2 = mesh_F[f * 3 + 2];
    const float cx = __fdiv_rn(__fadd_rn(__fadd_rn(mesh_V[i0*3+0], mesh_V[i1*3+0]), mesh_V[i2*3+0]), 3.0f);
    const float cy = __fdiv_rn(__fadd_rn(__fadd_rn(mesh_V[i0*3+1], mesh_V[i1*3+1]), mesh_V[i2*3+1]), 3.0f);
    const float cz = __fdiv_rn(__fadd_rn(__fadd_rn(mesh_V[i0*3+2], mesh_V[i1*3+2]), mesh_V[i2*3+2]), 3.0f);
    const float cc = __fadd_rn(__fadd_rn(__fmul_rn(cx, cx), __fmul_rn(cy, cy)),
                               __fmul_rn(cz, cz));
    cent[f] = make_float4(cx, cy, cz, cc);
}

// ---------------------------------------------------------------------------
// Kernel 1: KNN (K=1), 4 POINTS PER LANE + face-split x4.
// Round-6 analysis: the uniform-address float4 center loads are 64-lane
// broadcast VECTOR loads (~16 cyc L1-return each); 10k/CU ~= the 51 us.
// Amortize each load over 4 points/lane -> L1 time /4 (~17 us), VALU ~23 us.
// grid 256 x 1024: blockIdx = (point-group 0..63) x (face-quarter 0..3);
// 1 block/CU. Candidates to ws[4][kPts]; solve merges quarters (strict <,
// ascending quarter = ascending face index = first-occurrence ties).
// Per-(point,face) d2 tree is the frozen bit-exact *_rn sequence.
// ---------------------------------------------------------------------------
#define KNN_PARTS 16
#define KNN_SPLIT 4
constexpr int kQLen = kFaces / KNN_SPLIT;   // 2500

__global__ __launch_bounds__(1024)
void knn_kernel(const float* __restrict__ verts,
                const float4* __restrict__ cent,
                float*        __restrict__ ws_d2,   // [4][kPts]
                int*          __restrict__ ws_f)    // [4][kPts]
{
    __shared__ float s_best[KNN_PARTS * 256];
    __shared__ int   s_bestf[KNN_PARTS * 256];

    const int tid  = threadIdx.x;
    const int lane = tid & 63;
    const int part = __builtin_amdgcn_readfirstlane(tid >> 6);   // 0..15
    const int pgi  = blockIdx.x >> 2;       // 0..63
    const int quar = blockIdx.x & 3;        // 0..3
    const int p0   = pgi * 256 + lane;      // 4 points: p0 + 64*k

    // per-point query state (bit-exact q2 tree)
#define KNN_LOADQ(K)                                                                  \
    const float qx##K = verts[(p0 + 64 * (K)) * 3 + 0];                               \
    const float qy##K = verts[(p0 + 64 * (K)) * 3 + 1];                               \
    const float qz##K = verts[(p0 + 64 * (K)) * 3 + 2];                               \
    const float q2##K = __fadd_rn(__fadd_rn(__fmul_rn(qx##K, qx##K),                  \
                                            __fmul_rn(qy##K, qy##K)),                 \
                                  __fmul_rn(qz##K, qz##K));                           \
    float bd##K = INFINITY; int bf##K = 0x7fffffff;
    KNN_LOADQ(0) KNN_LOADQ(1) KNN_LOADQ(2) KNN_LOADQ(3)
#undef KNN_LOADQ

    const int fbeg = quar * kQLen + (part * kQLen) / KNN_PARTS;
    const int fend = quar * kQLen + ((part + 1) * kQLen) / KNN_PARTS;

#define KNN_EVAL(FF, C, K)                                                            \
    {                                                                                 \
        const float dot = __fadd_rn(__fadd_rn(__fmul_rn(qx##K, (C).x),                \
                                              __fmul_rn(qy##K, (C).y)),               \
                                    __fmul_rn(qz##K, (C).z));                         \
        const float d2 = __fsub_rn(__fadd_rn(q2##K, (C).w), __fmul_rn(2.0f, dot));    \
        if (d2 < bd##K) { bd##K = d2; bf##K = (FF); }                                 \
    }
#define KNN_EVAL4(FF, C) KNN_EVAL(FF, C, 0) KNN_EVAL(FF, C, 1) KNN_EVAL(FF, C, 2) KNN_EVAL(FF, C, 3)

    int f = fbeg;
    for (; f + 4 <= fend; f += 4) {
        const float4 c0 = cent[f + 0];   // uniform address, one load / 4-pt reuse
        const float4 c1 = cent[f + 1];
        const float4 c2 = cent[f + 2];
        const float4 c3 = cent[f + 3];
        KNN_EVAL4(f + 0, c0)
        KNN_EVAL4(f + 1, c1)
        KNN_EVAL4(f + 2, c2)
        KNN_EVAL4(f + 3, c3)
    }
    for (; f < fend; ++f) {
        const float4 c0 = cent[f];
        KNN_EVAL4(f, c0)
    }
#undef KNN_EVAL4
#undef KNN_EVAL

    // stage per-partition winners: layout [part][k][lane], lane-stride-1
    s_best [part * 256 + 0 * 64 + lane] = bd0;  s_bestf[part * 256 + 0 * 64 + lane] = bf0;
    s_best [part * 256 + 1 * 64 + lane] = bd1;  s_bestf[part * 256 + 1 * 64 + lane] = bf1;
    s_best [part * 256 + 2 * 64 + lane] = bd2;  s_bestf[part * 256 + 2 * 64 + lane] = bf2;
    s_best [part * 256 + 3 * 64 + lane] = bd3;  s_bestf[part * 256 + 3 * 64 + lane] = bf3;
    __syncthreads();
    if (part == 0) {
#pragma unroll
        for (int k = 0; k < 4; ++k) {
            float best  = s_best [k * 64 + lane];
            int   bestf = s_bestf[k * 64 + lane];
            for (int pt = 1; pt < KNN_PARTS; ++pt) {
                const float ob = s_best [pt * 256 + k * 64 + lane];
                const int   of = s_bestf[pt * 256 + k * 64 + lane];
                if (ob < best || (ob == best && of < bestf)) { best = ob; bestf = of; }
            }
            ws_d2[quar * kPts + p0 + 64 * k] = best;
            ws_f [quar * kPts + p0 + 64 * k] = bestf;
        }
    }
}

// ---------------------------------------------------------------------------
// Kernel 2: solve, 2 points per thread PACKED into float2 (v2) scalars.
// Round-6's PS-array version spilled (VGPR_Count=80 < state size) and only
// partially interleaved. v2 arithmetic lowers to v_pk_*_f32: one instruction
// drives both chains -> issue/point halves; no arrays -> no scratch.
// Per-element expression trees identical to rounds 5/6.
// 128 blocks x 64 threads; thread t handles p = t and p = t + 8192.
// ---------------------------------------------------------------------------
__global__ __launch_bounds__(64, 1)
void solve_kernel(const float* __restrict__ verts,
                  const float* __restrict__ mesh_V,
                  const float* __restrict__ mesh_N,
                  const int*   __restrict__ mesh_F,
                  const float* __restrict__ ws_d2,
                  const int*   __restrict__ ws_f,
                  float*       __restrict__ out)
{
    const int t = blockIdx.x * 64 + threadIdx.x;   // 0..8191
    int fsel[2];

#pragma unroll
    for (int k = 0; k < 2; ++k) {
        const int p = t + k * 8192;
        // merge quarters: strict < keeps lowest quarter (= smallest face
        // index) on ties == global first occurrence
        float best = ws_d2[p];
        int   bf   = ws_f[p];
#pragma unroll
        for (int q = 1; q < 4; ++q) {
            const float d = ws_d2[q * kPts + p];
            const int   ff = ws_f[q * kPts + p];
            if (d < best) { best = d; bf = ff; }
        }
        fsel[k] = bf;
        out[p] = (float)bf;
    }

#define LD2(arr, idx0, idx1) (v2){ arr[idx0], arr[idx1] }
    const int fA = fsel[0], fB = fsel[1];
    const int a0 = mesh_F[fA*3+0], a1 = mesh_F[fA*3+1], a2 = mesh_F[fA*3+2];
    const int b0 = mesh_F[fB*3+0], b1 = mesh_F[fB*3+1], b2 = mesh_F[fB*3+2];

    const v2 qx = LD2(verts, t*3+0, (t+8192)*3+0);
    const v2 qy = LD2(verts, t*3+1, (t+8192)*3+1);
    const v2 qz = LD2(verts, t*3+2, (t+8192)*3+2);

    const v2 V0x = LD2(mesh_V, a0*3+0, b0*3+0), V0y = LD2(mesh_V, a0*3+1, b0*3+1), V0z = LD2(mesh_V, a0*3+2, b0*3+2);
    const v2 V1x = LD2(mesh_V, a1*3+0, b1*3+0), V1y = LD2(mesh_V, a1*3+1, b1*3+1), V1z = LD2(mesh_V, a1*3+2, b1*3+2);
    const v2 V2x = LD2(mesh_V, a2*3+0, b2*3+0), V2y = LD2(mesh_V, a2*3+1, b2*3+1), V2z = LD2(mesh_V, a2*3+2, b2*3+2);
    const v2 N0x = LD2(mesh_N, a0*3+0, b0*3+0), N0y = LD2(mesh_N, a0*3+1, b0*3+1), N0z = LD2(mesh_N, a0*3+2, b0*3+2);
    const v2 N1x = LD2(mesh_N, a1*3+0, b1*3+0), N1y = LD2(mesh_N, a1*3+1, b1*3+1), N1z = LD2(mesh_N, a1*3+2, b1*3+2);
    const v2 N2x = LD2(mesh_N, a2*3+0, b2*3+0), N2y = LD2(mesh_N, a2*3+1, b2*3+1), N2z = LD2(mesh_N, a2*3+2, b2*3+2);
#undef LD2

    const v2 E0x = V0x - V2x, E0y = V0y - V2y, E0z = V0z - V2z;
    const v2 E1x = V1x - V2x, E1y = V1y - V2y, E1z = V1z - V2z;
    const v2 F0x = N0x - N2x, F0y = N0y - N2y, F0z = N0z - N2z;
    const v2 F1x = N1x - N2x, F1y = N1y - N2y, F1z = N1z - N2z;

    const v2 txv = qx * SCALE, tyv = qy * SCALE, tzv = qz * SCALE;
    const float GS = 2.0f / (3.0f * 16384.0f);
    const float B1 = 0.9f,  ONE_M_B1 = 1.0f - 0.9f;
    const float B2 = 0.999f, ONE_M_B2 = 1.0f - 0.999f;

    v2 vwu = (v2)(1.0f / 3.0f), vwv = (v2)(1.0f / 3.0f);

    for (int outer = 0; outer < kOuter; ++outer) {
        const v2 bw0 = (1.0f - vwu) - vwv;
        const v2 px = ((vwu * V0x + vwv * V1x) + bw0 * V2x);
        const v2 py = ((vwu * V0y + vwv * V1y) + bw0 * V2y);
        const v2 pz = ((vwu * V0z + vwv * V1z) + bw0 * V2z);
        const v2 dx = px - qx, dy = py - qy, dz = pz - qz;
        const v2 dn = (dx * dx + dy * dy) + dz * dz;
        v2 dd;
        dd.x = __builtin_amdgcn_sqrtf(dn.x);
        dd.y = __builtin_amdgcn_sqrtf(dn.y);

        v2 du = (v2)0.0f, dv = (v2)0.0f;
        v2 mAu = (v2)0.0f, mAv = (v2)0.0f, mAd = (v2)0.0f;
        v2 vAu = (v2)0.0f, vAv = (v2)0.0f, vAd = (v2)0.0f;

#pragma unroll 2
        for (int it = 0; it < kInner; ++it) {
            const float rb1 = kTab.rb[2 * it + 0];   // uniform s_load, both chains
            const float rb2 = kTab.rb[2 * it + 1];

            const v2 bu = vwu + du;
            const v2 bv = vwv + dv;
            const v2 bw = (1.0f - bu) - bv;

            const v2 cVx = ((bu * V0x + bv * V1x) + bw * V2x) * SCALE;
            const v2 cVy = ((bu * V0y + bv * V1y) + bw * V2y) * SCALE;
            const v2 cVz = ((bu * V0z + bv * V1z) + bw * V2z) * SCALE;

            const v2 nrx = (bu * N0x + bv * N1x) + bw * N2x;
            const v2 nry = (bu * N0y + bv * N1y) + bw * N2y;
            const v2 nrz = (bu * N0z + bv * N1z) + bw * N2z;
            const v2 nn  = (nrx * nrx + nry * nry) + nrz * nrz;
            v2 inv;
            inv.x = __builtin_amdgcn_rsqf(nn.x);
            inv.y = __builtin_amdgcn_rsqf(nn.y);
            const v2 nhx = nrx * inv, nhy = nry * inv, nhz = nrz * inv;
            const v2 cNx = nhx * SCALE, cNy = nhy * SCALE, cNz = nhz * SCALE;

            const v2 rx = (cVx + cNx * dd) - txv;
            const v2 ry = (cVy + cNy * dd) - tyv;
            const v2 rz = (cVz + cNz * dd) - tzv;

            const v2 rv0  = (rx * E0x + ry * E0y) + rz * E0z;
            const v2 rv1  = (rx * E1x + ry * E1y) + rz * E1z;
            const v2 rn0  = (rx * F0x + ry * F0y) + rz * F0z;
            const v2 rn1  = (rx * F1x + ry * F1y) + rz * F1z;
            const v2 nf0  = (nhx * F0x + nhy * F0y) + nhz * F0z;
            const v2 nf1  = (nhx * F1x + nhy * F1y) + nhz * F1z;
            const v2 nr_r = (nhx * rx + nhy * ry) + nhz * rz;

            const v2 gu = GS * (SCALE * rv0 + (dd * SCALE) * ((rn0 - nr_r * nf0) * inv));
            const v2 gv = GS * (SCALE * rv1 + (dd * SCALE) * ((rn1 - nr_r * nf1) * inv));
            const v2 gd = GS * (SCALE * nr_r);

            mAu = B1 * mAu + ONE_M_B1 * gu;
            mAv = B1 * mAv + ONE_M_B1 * gv;
            mAd = B1 * mAd + ONE_M_B1 * gd;
            vAu = B2 * vAu + ONE_M_B2 * (gu * gu);
            vAv = B2 * vAv + ONE_M_B2 * (gv * gv);
            vAd = B2 * vAd + ONE_M_B2 * (gd * gd);

            const v2 au = vAu * rb2 + 1e-16f;
            const v2 av = vAv * rb2 + 1e-16f;
            const v2 ad = vAd * rb2 + 1e-16f;
            v2 su, sv, sd;
            su.x = __builtin_amdgcn_rsqf(au.x);  su.y = __builtin_amdgcn_rsqf(au.y);
            sv.x = __builtin_amdgcn_rsqf(av.x);  sv.y = __builtin_amdgcn_rsqf(av.y);
            sd.x = __builtin_amdgcn_rsqf(ad.x);  sd.y = __builtin_amdgcn_rsqf(ad.y);
            du -= 0.01f * (mAu * rb1) * su;
            dv -= 0.01f * (mAv * rb1) * sv;
            dd -= 0.01f * (mAd * rb1) * sd;
        }
        vwu += du;
        vwv += dv;
    }

#pragma unroll
    for (int k = 0; k < 2; ++k) {
        const int p = t + k * 8192;
        const float u = (k == 0) ? vwu.x : vwu.y;
        const float v = (k == 0) ? vwv.x : vwv.y;
        out[kPts + 2 * p + 0] = u;
        out[kPts + 2 * p + 1] = v;
        out[3 * kPts + p]     = 0.0f;   // outlier_mask = False
    }
}

extern "C" void kernel_launch(void* const* d_in, const int* in_sizes, int n_in,
                              void* d_out, int out_size, void* d_ws, size_t ws_size,
                              hipStream_t stream) {
    const float* verts  = (const float*)d_in[0];
    const float* mesh_V = (const float*)d_in[1];
    const float* mesh_N = (const float*)d_in[2];
    const int*   mesh_F = (const int*)d_in[3];
    float* out = (float*)d_out;

    // workspace: centers | d2 candidates [4][kPts] | face candidates [4][kPts]
    float4* ws_cent = (float4*)d_ws;                                    // 160 KB
    float*  ws_d2   = (float*)((char*)d_ws + kFaces * sizeof(float4));  // 256 KB
    int*    ws_f    = (int*)((char*)ws_d2 + 4 * kPts * sizeof(float));  // 256 KB

    hipLaunchKernelGGL(centers_kernel, dim3((kFaces + 255) / 256), dim3(256), 0, stream,
                       mesh_V, mesh_F, ws_cent);
    hipLaunchKernelGGL(knn_kernel,     dim3((kPts / 256) * KNN_SPLIT), dim3(1024), 0, stream,
                       verts, ws_cent, ws_d2, ws_f);
    hipLaunchKernelGGL(solve_kernel,   dim3(8192 / 64), dim3(64), 0, stream,
                       verts, mesh_V, mesh_N, mesh_F, ws_d2, ws_f, out);
}